// Round 5
// baseline (46.111 us; speedup 1.0000x reference)
//
#include <hip/hip_runtime.h>
#include <math.h>

// YOLO loss, MI355X.
//   pred_pS: (32, 85, H, W) fp32, channel stride = H*W
//   tgt_boxes: (32, 50, 4) fp32 ; tgt_cls: (32, 50) int32
//   scales: HW = 6400 / 1600 / 400, fw = 80 / 40 / 20
// n_obj == 50 always; scatter never collides; cls denominator = 4000.
//   per (b,s): obj = (1/HW)[1.5*sum_all sp(po) - sum_obj(po + 0.5*sp(po))]
//   bbox = 5*sum_obj sum_k (pb-t)^2 ; cls = sum_obj [sum_c sp(pc) - pc[tgt]]
//
// R1 atomics 357us -> R2 partials 17.6 -> R3 fuse regression 18.9 ->
// R4 transposed gather 14.0. R5 (this): HYBRID. p4+p5 are line-bound under
// gather (39/100 and 22/25 lines touched per plane) -> stream them densely
// with an LDS obj-mask per 200-cell chunk; p3 (47/400 lines) keeps the
// R4 plane-local gather. Scattered traffic drops 21 -> 8.2 MB.

#define P3D_BLOCKS 200              // p3 ch4 plane: 51200 float4
#define P4_BLOCKS  256              // 32 b * 8 chunks of 200 cells
#define P5_BLOCKS  64               // 32 b * 2 chunks of 200 cells
#define P3G_BLOCKS 176              // 704 waves = 32 b * 22 ch-groups
#define NB_P3D P3D_BLOCKS                   // 200
#define NB_P4  (NB_P3D + P4_BLOCKS)         // 456
#define NB_P5  (NB_P4 + P5_BLOCKS)          // 520
#define TOTAL_BLOCKS (NB_P5 + P3G_BLOCKS)   // 696

__device__ __forceinline__ float softplusf(float x) {
    // logaddexp(0, x) = max(x,0) + log1p(exp(-|x|))
    return fmaxf(x, 0.0f) + log1pf(__expf(-fabsf(x)));
}

__global__ __launch_bounds__(256)
void yolo_loss_partial(const float* __restrict__ p3,
                       const float* __restrict__ p4,
                       const float* __restrict__ p5,
                       const float* __restrict__ tb,
                       const int*   __restrict__ tc,
                       float* __restrict__ ws)
{
    const int lane = threadIdx.x & 63;
    const int wid  = threadIdx.x >> 6;
    __shared__ float red[4][3];
    __shared__ signed char boxid[200];   // rel cell -> box index or -1
    __shared__ float tbox[200];          // [box*4 + comp]
    __shared__ int   tgs[50];

    float vb = 0.f, vo = 0.f, vc = 0.f;
    const int blk = blockIdx.x;

    if (blk < NB_P3D) {
        // ---- p3 channel-4 plane, dense float4 (S part of obj loss) ----
        int i = blk * 256 + threadIdx.x;
        if (i < 51200) {                            // 32 * 1600 float4
            int b = i / 1600, o = i - b * 1600;
            const float4 dv = *(const float4*)(p3 + ((size_t)b * 85 + 4) * 6400 + o * 4);
            vo = (softplusf(dv.x) + softplusf(dv.y) +
                  softplusf(dv.z) + softplusf(dv.w)) * (1.5f / 6400.f);
        }
    } else if (blk < NB_P5) {
        // ---- dense-streamed p4 / p5 chunk: 200 cells x 85 channels ----
        const float* pred; int fw, hw, b, c0; float invHW;
        if (blk < NB_P4) {
            int j = blk - NB_P3D; b = j >> 3; c0 = (j & 7) * 200;
            pred = p4; fw = 40; hw = 1600; invHW = 1.f / 1600.f;
        } else {
            int j = blk - NB_P4; b = j >> 1; c0 = (j & 1) * 200;
            pred = p5; fw = 20; hw = 400; invHW = 1.f / 400.f;
        }

        for (int i = threadIdx.x; i < 200; i += 256) boxid[i] = (signed char)-1;
        __syncthreads();
        if (threadIdx.x < 50) {
            const float4 t4 = *(const float4*)(tb + (size_t)(b * 50 + threadIdx.x) * 4);
            tbox[threadIdx.x * 4 + 0] = t4.x;
            tbox[threadIdx.x * 4 + 1] = t4.y;
            tbox[threadIdx.x * 4 + 2] = t4.z;
            tbox[threadIdx.x * 4 + 3] = t4.w;
            tgs[threadIdx.x] = tc[b * 50 + threadIdx.x];
            // exact reference grid-index math (f32 mul, trunc, clip)
            int gx = (int)(t4.x * (float)fw); gx = min(max(gx, 0), fw - 1);
            int gy = (int)(t4.y * (float)fw); gy = min(max(gy, 0), fw - 1);
            int rel = gy * fw + gx - c0;
            if (rel >= 0 && rel < 200) boxid[rel] = (signed char)threadIdx.x;
        }
        __syncthreads();

        const float* bp = pred + (size_t)b * 85 * hw + c0;
        auto proc = [&](float vv, int ch, int rel) {
            int bid = boxid[rel];
            if (ch == 4) {
                float s = softplusf(vv);
                vo += 1.5f * s * invHW;
                if (bid >= 0) vo -= (vv + 0.5f * s) * invHW;
            } else if (bid >= 0) {
                if (ch < 4) {
                    float d = vv - tbox[bid * 4 + ch];
                    vb += d * d;
                } else {
                    vc += softplusf(vv) - ((ch - 5) == tgs[bid] ? vv : 0.f);
                }
            }
        };
        for (int i4 = threadIdx.x; i4 < 85 * 50; i4 += 256) {
            int ch = i4 / 50, c4 = i4 - ch * 50;
            const float4 v = *(const float4*)(bp + (size_t)ch * hw + c4 * 4);
            int rel = c4 * 4;
            proc(v.x, ch, rel + 0);
            proc(v.y, ch, rel + 1);
            proc(v.z, ch, rel + 2);
            proc(v.w, ch, rel + 3);
        }
    } else {
        // ---- p3 gather: wave = (batch, 4-channel group); lane = box ----
        int w = (blk - NB_P5) * 4 + wid;            // [0, 704)
        int b = w / 22;
        int g = w - b * 22;
        int c0 = g * 4;
        const float invHW = 1.f / 6400.f;

        if (lane < 50) {
            const float4 t4 = *(const float4*)(tb + (size_t)(b * 50 + lane) * 4);
            int tgt = tc[b * 50 + lane];

            int gx = (int)(t4.x * 80.f); gx = min(max(gx, 0), 79);
            int gy = (int)(t4.y * 80.f); gy = min(max(gy, 0), 79);
            const float* base = p3 + (size_t)b * 85 * 6400 + gy * 80 + gx;

            float v0 = base[(size_t)c0 * 6400];
            float v1 = (c0 + 1 < 85) ? base[(size_t)(c0 + 1) * 6400] : 0.f;
            float v2 = (c0 + 2 < 85) ? base[(size_t)(c0 + 2) * 6400] : 0.f;
            float v3 = (c0 + 3 < 85) ? base[(size_t)(c0 + 3) * 6400] : 0.f;

            if (g == 0) {
                float d0 = v0 - t4.x, d1 = v1 - t4.y;
                float d2 = v2 - t4.z, d3 = v3 - t4.w;
                vb = d0 * d0 + d1 * d1 + d2 * d2 + d3 * d3;
            } else if (g == 1) {
                vo  = -(v0 + 0.5f * softplusf(v0)) * invHW;   // obj fixup
                vc  = softplusf(v1) - (0 == tgt ? v1 : 0.f);
                vc += softplusf(v2) - (1 == tgt ? v2 : 0.f);
                vc += softplusf(v3) - (2 == tgt ? v3 : 0.f);
            } else {
                vc  = softplusf(v0) - ((c0 - 5) == tgt ? v0 : 0.f);
                if (c0 + 1 < 85) vc += softplusf(v1) - ((c0 - 4) == tgt ? v1 : 0.f);
                if (c0 + 2 < 85) vc += softplusf(v2) - ((c0 - 3) == tgt ? v2 : 0.f);
                if (c0 + 3 < 85) vc += softplusf(v3) - ((c0 - 2) == tgt ? v3 : 0.f);
            }
        }
    }

    vb *= (5.f / 96.f);             // LAMBDA_COORD / (B*3)
    vo *= (1.f / 96.f);             // / (B*3)
    vc *= (1.f / (4000.f * 96.f));  // / (n_obj*NUM_CLASSES) / (B*3)

    #pragma unroll
    for (int off = 1; off < 64; off <<= 1) {
        vb += __shfl_xor(vb, off, 64);
        vo += __shfl_xor(vo, off, 64);
        vc += __shfl_xor(vc, off, 64);
    }

    if (lane == 0) { red[wid][0] = vb; red[wid][1] = vo; red[wid][2] = vc; }
    __syncthreads();
    if (threadIdx.x == 0) {
        float b0 = red[0][0] + red[1][0] + red[2][0] + red[3][0];
        float o0 = red[0][1] + red[1][1] + red[2][1] + red[3][1];
        float c0s = red[0][2] + red[1][2] + red[2][2] + red[3][2];
        ((float4*)ws)[blockIdx.x] = make_float4(b0, o0, c0s, 0.f);
    }
}

__global__ __launch_bounds__(256)
void yolo_loss_final(const float* __restrict__ ws, float* __restrict__ out)
{
    const int lane = threadIdx.x & 63;
    const int wid  = threadIdx.x >> 6;
    __shared__ float red[4][3];

    float sb = 0.f, so = 0.f, sc = 0.f;
    for (int i = threadIdx.x; i < TOTAL_BLOCKS; i += 256) {
        const float4 v = ((const float4*)ws)[i];
        sb += v.x; so += v.y; sc += v.z;
    }
    #pragma unroll
    for (int off = 1; off < 64; off <<= 1) {
        sb += __shfl_xor(sb, off, 64);
        so += __shfl_xor(so, off, 64);
        sc += __shfl_xor(sc, off, 64);
    }
    if (lane == 0) { red[wid][0] = sb; red[wid][1] = so; red[wid][2] = sc; }
    __syncthreads();
    if (threadIdx.x == 0) {
        float b0 = red[0][0] + red[1][0] + red[2][0] + red[3][0];
        float o0 = red[0][1] + red[1][1] + red[2][1] + red[3][1];
        float c0 = red[0][2] + red[1][2] + red[2][2] + red[3][2];
        out[0] = b0;
        out[1] = o0;
        out[2] = c0;
        out[3] = b0 + o0 + c0;
    }
}

extern "C" void kernel_launch(void* const* d_in, const int* in_sizes, int n_in,
                              void* d_out, int out_size, void* d_ws, size_t ws_size,
                              hipStream_t stream) {
    const float* p3 = (const float*)d_in[0];
    const float* p4 = (const float*)d_in[1];
    const float* p5 = (const float*)d_in[2];
    const float* tb = (const float*)d_in[3];
    const int*   tc = (const int*)d_in[4];
    float* out = (float*)d_out;
    float* ws  = (float*)d_ws;   // needs TOTAL_BLOCKS*16 B = 11.1 KB

    hipLaunchKernelGGL(yolo_loss_partial,
                       dim3(TOTAL_BLOCKS), dim3(256), 0, stream,
                       p3, p4, p5, tb, tc, ws);
    hipLaunchKernelGGL(yolo_loss_final,
                       dim3(1), dim3(256), 0, stream,
                       ws, out);
}

// Round 6
// 35.590 us; speedup vs baseline: 1.2956x; 1.2956x over previous
//
#include <hip/hip_runtime.h>
#include <math.h>

// YOLO loss, MI355X.
//   pred_pS: (32, 85, H, W) fp32, channel stride = H*W
//   tgt_boxes: (32, 50, 4) fp32 ; tgt_cls: (32, 50) int32
//   scales: HW = 6400 / 1600 / 400, fw = 80 / 40 / 20
// n_obj == 50 always; scatter never collides; cls denominator = 4000.
//   per (b,s): obj = (1/HW)[1.5*sum_all sp(po) - sum_obj(po + 0.5*sp(po))]
//   bbox = 5*sum_obj sum_k (pb-t)^2 ; cls = sum_obj [sum_c sp(pc) - pc[tgt]]
//
// R1 atomics 357us -> R2 partials 17.6 -> R3 fuse-dense regression 18.9 ->
// R4 transposed plane-local gather 14.0 -> R5 masked dense sweep regression
// 46.1 (mask lookup is compute-bound; reverted).
// R6 (this): exact R4 gather structure + final reduction fused via ticket
// counter (memset node + agent-scope atomics), removing the second kernel.

#define DENSE_V4_TOTAL 67200        // 268800 floats / 4
#define DENSE_BLOCKS 263            // ceil(67200/256)
#define SP_GROUPS 22                // ceil(85 channels / 4)
#define SPARSE_BLOCKS 528           // 2112 waves = 96 (s,b) * 22 groups
#define TOTAL_BLOCKS (DENSE_BLOCKS + SPARSE_BLOCKS)   // 791
#define CNT_OFF 12672               // byte offset of ticket counter in ws

__device__ __forceinline__ float softplusf(float x) {
    // logaddexp(0, x) = max(x,0) + log1p(exp(-|x|))
    return fmaxf(x, 0.0f) + log1pf(__expf(-fabsf(x)));
}

__global__ __launch_bounds__(256)
void yolo_loss_fused(const float* __restrict__ p3,
                     const float* __restrict__ p4,
                     const float* __restrict__ p5,
                     const float* __restrict__ tb,
                     const int*   __restrict__ tc,
                     float* __restrict__ ws,
                     unsigned int* __restrict__ cnt,
                     float* __restrict__ out)
{
    const int lane = threadIdx.x & 63;
    const int wid  = threadIdx.x >> 6;
    __shared__ float red[4][3];
    __shared__ unsigned int sh_last;

    float vb = 0.f, vo = 0.f, vc = 0.f;

    if (blockIdx.x < DENSE_BLOCKS) {
        // ---- dense: softplus over channel-4 planes, float4-vectorized ----
        int i = blockIdx.x * 256 + threadIdx.x;
        if (i < DENSE_V4_TOTAL) {
            const float* dp; float dscale;
            if (i < 51200) {                        // p3: 32 * 1600 float4
                int b = i / 1600, o = i - b * 1600;
                dp = p3 + ((size_t)b * 85 + 4) * 6400 + o * 4;
                dscale = 1.5f / 6400.f;
            } else if (i < 64000) {                 // p4: 32 * 400 float4
                int j = i - 51200;
                int b = j / 400, o = j - b * 400;
                dp = p4 + ((size_t)b * 85 + 4) * 1600 + o * 4;
                dscale = 1.5f / 1600.f;
            } else {                                // p5: 32 * 100 float4
                int j = i - 64000;
                int b = j / 100, o = j - b * 100;
                dp = p5 + ((size_t)b * 85 + 4) * 400 + o * 4;
                dscale = 1.5f / 400.f;
            }
            float4 dv = *(const float4*)dp;
            vo = (softplusf(dv.x) + softplusf(dv.y) +
                  softplusf(dv.z) + softplusf(dv.w)) * dscale;
        }
    } else {
        // ---- sparse: wave = (scale, batch, channel-group); lane = box ----
        int w  = (blockIdx.x - DENSE_BLOCKS) * 4 + wid;   // [0, 2112)
        int sb = w / SP_GROUPS;                           // [0, 96)
        int g  = w - sb * SP_GROUPS;                      // [0, 22)
        int s  = sb >> 5;
        int b  = sb & 31;
        int c0 = g * 4;

        const float* pred; int fw, hw; float invHW;
        if (s == 0)      { pred = p3; fw = 80; hw = 6400; invHW = 1.f / 6400.f; }
        else if (s == 1) { pred = p4; fw = 40; hw = 1600; invHW = 1.f / 1600.f; }
        else             { pred = p5; fw = 20; hw = 400;  invHW = 1.f / 400.f;  }

        if (lane < 50) {
            const float4 t4 = *(const float4*)(tb + ((size_t)(b * 50 + lane)) * 4);
            int tgt = tc[b * 50 + lane];

            // exact reference grid-index math (f32 mul, trunc, clip)
            int gx = (int)(t4.x * (float)fw); gx = min(max(gx, 0), fw - 1);
            int gy = (int)(t4.y * (float)fw); gy = min(max(gy, 0), fw - 1);
            const float* base = pred + (size_t)b * 85 * hw + gy * fw + gx;

            float v0 = base[(size_t)c0 * hw];
            float v1 = (c0 + 1 < 85) ? base[(size_t)(c0 + 1) * hw] : 0.f;
            float v2 = (c0 + 2 < 85) ? base[(size_t)(c0 + 2) * hw] : 0.f;
            float v3 = (c0 + 3 < 85) ? base[(size_t)(c0 + 3) * hw] : 0.f;

            if (g == 0) {
                // channels 0..3 -> bbox
                float d0 = v0 - t4.x, d1 = v1 - t4.y;
                float d2 = v2 - t4.z, d3 = v3 - t4.w;
                vb = d0 * d0 + d1 * d1 + d2 * d2 + d3 * d3;
            } else if (g == 1) {
                // channel 4 -> obj fixup; 5..7 -> cls
                vo  = -(v0 + 0.5f * softplusf(v0)) * invHW;
                vc  = softplusf(v1) - (0 == tgt ? v1 : 0.f);
                vc += softplusf(v2) - (1 == tgt ? v2 : 0.f);
                vc += softplusf(v3) - (2 == tgt ? v3 : 0.f);
            } else {
                // channels c0..c0+3 (c0 >= 8) -> cls; guard c0+k < 85
                vc  = softplusf(v0) - ((c0 - 5) == tgt ? v0 : 0.f);
                if (c0 + 1 < 85) vc += softplusf(v1) - ((c0 - 4) == tgt ? v1 : 0.f);
                if (c0 + 2 < 85) vc += softplusf(v2) - ((c0 - 3) == tgt ? v2 : 0.f);
                if (c0 + 3 < 85) vc += softplusf(v3) - ((c0 - 2) == tgt ? v3 : 0.f);
            }
        }
    }

    vb *= (5.f / 96.f);             // LAMBDA_COORD / (B*3)
    vo *= (1.f / 96.f);             // / (B*3)
    vc *= (1.f / (4000.f * 96.f));  // / (n_obj*NUM_CLASSES) / (B*3)

    #pragma unroll
    for (int off = 1; off < 64; off <<= 1) {
        vb += __shfl_xor(vb, off, 64);
        vo += __shfl_xor(vo, off, 64);
        vc += __shfl_xor(vc, off, 64);
    }

    if (lane == 0) { red[wid][0] = vb; red[wid][1] = vo; red[wid][2] = vc; }
    __syncthreads();

    if (threadIdx.x == 0) {
        float b0 = red[0][0] + red[1][0] + red[2][0] + red[3][0];
        float o0 = red[0][1] + red[1][1] + red[2][1] + red[3][1];
        float c0s = red[0][2] + red[1][2] + red[2][2] + red[3][2];
        // publish partial with agent-scope (cross-XCD coherent) stores
        float* slot = ws + (size_t)blockIdx.x * 4;
        __hip_atomic_store(&slot[0], b0, __ATOMIC_RELAXED, __HIP_MEMORY_SCOPE_AGENT);
        __hip_atomic_store(&slot[1], o0, __ATOMIC_RELAXED, __HIP_MEMORY_SCOPE_AGENT);
        __hip_atomic_store(&slot[2], c0s, __ATOMIC_RELAXED, __HIP_MEMORY_SCOPE_AGENT);
        // ticket: release our stores, acquire everyone else's
        unsigned int t = __hip_atomic_fetch_add(cnt, 1u, __ATOMIC_ACQ_REL,
                                                __HIP_MEMORY_SCOPE_AGENT);
        sh_last = (t == TOTAL_BLOCKS - 1) ? 1u : 0u;
    }
    __syncthreads();

    if (sh_last) {
        // ---- last-arriving block: reduce all partials, write out ----
        float sb = 0.f, so = 0.f, sc = 0.f;
        for (int i = threadIdx.x; i < TOTAL_BLOCKS; i += 256) {
            const float* slot = ws + (size_t)i * 4;
            sb += __hip_atomic_load(&slot[0], __ATOMIC_RELAXED, __HIP_MEMORY_SCOPE_AGENT);
            so += __hip_atomic_load(&slot[1], __ATOMIC_RELAXED, __HIP_MEMORY_SCOPE_AGENT);
            sc += __hip_atomic_load(&slot[2], __ATOMIC_RELAXED, __HIP_MEMORY_SCOPE_AGENT);
        }
        #pragma unroll
        for (int off = 1; off < 64; off <<= 1) {
            sb += __shfl_xor(sb, off, 64);
            so += __shfl_xor(so, off, 64);
            sc += __shfl_xor(sc, off, 64);
        }
        if (lane == 0) { red[wid][0] = sb; red[wid][1] = so; red[wid][2] = sc; }
        __syncthreads();
        if (threadIdx.x == 0) {
            float b0 = red[0][0] + red[1][0] + red[2][0] + red[3][0];
            float o0 = red[0][1] + red[1][1] + red[2][1] + red[3][1];
            float c0 = red[0][2] + red[1][2] + red[2][2] + red[3][2];
            out[0] = b0;
            out[1] = o0;
            out[2] = c0;
            out[3] = b0 + o0 + c0;
        }
    }
}

extern "C" void kernel_launch(void* const* d_in, const int* in_sizes, int n_in,
                              void* d_out, int out_size, void* d_ws, size_t ws_size,
                              hipStream_t stream) {
    const float* p3 = (const float*)d_in[0];
    const float* p4 = (const float*)d_in[1];
    const float* p5 = (const float*)d_in[2];
    const float* tb = (const float*)d_in[3];
    const int*   tc = (const int*)d_in[4];
    float* out = (float*)d_out;
    float* ws  = (float*)d_ws;                       // partials: 791*16 B
    unsigned int* cnt = (unsigned int*)((char*)d_ws + CNT_OFF);

    // zero the ticket counter every call (graph-capture-safe async memset)
    hipMemsetAsync(cnt, 0, sizeof(unsigned int), stream);

    hipLaunchKernelGGL(yolo_loss_fused,
                       dim3(TOTAL_BLOCKS), dim3(256), 0, stream,
                       p3, p4, p5, tb, tc, ws, cnt, out);
}

// Round 7
// 13.875 us; speedup vs baseline: 3.3234x; 2.5651x over previous
//
#include <hip/hip_runtime.h>
#include <math.h>

// YOLO loss, MI355X.
//   pred_pS: (32, 85, H, W) fp32, channel stride = H*W
//   tgt_boxes: (32, 50, 4) fp32 ; tgt_cls: (32, 50) int32
//   scales: HW = 6400 / 1600 / 400, fw = 80 / 40 / 20
// n_obj == 50 always; scatter never collides; cls denominator = 4000.
//   per (b,s): obj = (1/HW)[1.5*sum_all sp(po) - sum_obj(po + 0.5*sp(po))]
//   bbox = 5*sum_obj sum_k (pb-t)^2 ; cls = sum_obj [sum_c sp(pc) - pc[tgt]]
//
// History: R1 same-line atomics 357us -> R2 two-kernel partials 17.6 ->
// R3 dense-into-sparse fuse 18.9 (regr) -> R4 transposed plane-local gather
// 14.0 (best) -> R5 masked dense sweep 46.1 (regr: mask lookup compute-bound)
// -> R6 ticket-fused single kernel 35.6 (regr: per-block agent-scope fence /
// memset node). R7 (this): exact R4 revert + sparse blocks dispatched FIRST
// (long-pole scattered waves start earliest; dense ch-4 pass back-fills).
// Two kernels, no atomics, no memset: kernel boundary provides coherence.

#define DENSE_V4_TOTAL 67200        // 268800 floats / 4
#define DENSE_BLOCKS 263            // ceil(67200/256)
#define SP_GROUPS 22                // ceil(85 channels / 4)
#define SPARSE_BLOCKS 528           // 2112 waves = 96 (s,b) * 22 groups
#define TOTAL_BLOCKS (DENSE_BLOCKS + SPARSE_BLOCKS)   // 791

__device__ __forceinline__ float softplusf(float x) {
    // logaddexp(0, x) = max(x,0) + log1p(exp(-|x|))
    return fmaxf(x, 0.0f) + log1pf(__expf(-fabsf(x)));
}

__global__ __launch_bounds__(256)
void yolo_loss_partial(const float* __restrict__ p3,
                       const float* __restrict__ p4,
                       const float* __restrict__ p5,
                       const float* __restrict__ tb,
                       const int*   __restrict__ tc,
                       float* __restrict__ ws)
{
    const int lane = threadIdx.x & 63;
    const int wid  = threadIdx.x >> 6;
    __shared__ float red[4][3];

    float vb = 0.f, vo = 0.f, vc = 0.f;

    if (blockIdx.x < SPARSE_BLOCKS) {
        // ---- sparse: wave = (scale, batch, channel-group); lane = box ----
        // dispatched first: these scattered-latency waves are the long pole
        int w  = blockIdx.x * 4 + wid;                    // [0, 2112)
        int sb = w / SP_GROUPS;                           // [0, 96)
        int g  = w - sb * SP_GROUPS;                      // [0, 22)
        int s  = sb >> 5;
        int b  = sb & 31;
        int c0 = g * 4;

        const float* pred; int fw, hw; float invHW;
        if (s == 0)      { pred = p3; fw = 80; hw = 6400; invHW = 1.f / 6400.f; }
        else if (s == 1) { pred = p4; fw = 40; hw = 1600; invHW = 1.f / 1600.f; }
        else             { pred = p5; fw = 20; hw = 400;  invHW = 1.f / 400.f;  }

        if (lane < 50) {
            const float4 t4 = *(const float4*)(tb + ((size_t)(b * 50 + lane)) * 4);
            int tgt = tc[b * 50 + lane];

            // exact reference grid-index math (f32 mul, trunc, clip)
            int gx = (int)(t4.x * (float)fw); gx = min(max(gx, 0), fw - 1);
            int gy = (int)(t4.y * (float)fw); gy = min(max(gy, 0), fw - 1);
            const float* base = pred + (size_t)b * 85 * hw + gy * fw + gx;

            float v0 = base[(size_t)c0 * hw];
            float v1 = (c0 + 1 < 85) ? base[(size_t)(c0 + 1) * hw] : 0.f;
            float v2 = (c0 + 2 < 85) ? base[(size_t)(c0 + 2) * hw] : 0.f;
            float v3 = (c0 + 3 < 85) ? base[(size_t)(c0 + 3) * hw] : 0.f;

            if (g == 0) {
                // channels 0..3 -> bbox
                float d0 = v0 - t4.x, d1 = v1 - t4.y;
                float d2 = v2 - t4.z, d3 = v3 - t4.w;
                vb = d0 * d0 + d1 * d1 + d2 * d2 + d3 * d3;
            } else if (g == 1) {
                // channel 4 -> obj fixup; 5..7 -> cls
                vo  = -(v0 + 0.5f * softplusf(v0)) * invHW;
                vc  = softplusf(v1) - (0 == tgt ? v1 : 0.f);
                vc += softplusf(v2) - (1 == tgt ? v2 : 0.f);
                vc += softplusf(v3) - (2 == tgt ? v3 : 0.f);
            } else {
                // channels c0..c0+3 (c0 >= 8) -> cls; guard c0+k < 85
                vc  = softplusf(v0) - ((c0 - 5) == tgt ? v0 : 0.f);
                if (c0 + 1 < 85) vc += softplusf(v1) - ((c0 - 4) == tgt ? v1 : 0.f);
                if (c0 + 2 < 85) vc += softplusf(v2) - ((c0 - 3) == tgt ? v2 : 0.f);
                if (c0 + 3 < 85) vc += softplusf(v3) - ((c0 - 2) == tgt ? v3 : 0.f);
            }
        }
    } else {
        // ---- dense: softplus over channel-4 planes, float4-vectorized ----
        int i = (blockIdx.x - SPARSE_BLOCKS) * 256 + threadIdx.x;
        if (i < DENSE_V4_TOTAL) {
            const float* dp; float dscale;
            if (i < 51200) {                        // p3: 32 * 1600 float4
                int b = i / 1600, o = i - b * 1600;
                dp = p3 + ((size_t)b * 85 + 4) * 6400 + o * 4;
                dscale = 1.5f / 6400.f;
            } else if (i < 64000) {                 // p4: 32 * 400 float4
                int j = i - 51200;
                int b = j / 400, o = j - b * 400;
                dp = p4 + ((size_t)b * 85 + 4) * 1600 + o * 4;
                dscale = 1.5f / 1600.f;
            } else {                                // p5: 32 * 100 float4
                int j = i - 64000;
                int b = j / 100, o = j - b * 100;
                dp = p5 + ((size_t)b * 85 + 4) * 400 + o * 4;
                dscale = 1.5f / 400.f;
            }
            float4 dv = *(const float4*)dp;
            vo = (softplusf(dv.x) + softplusf(dv.y) +
                  softplusf(dv.z) + softplusf(dv.w)) * dscale;
        }
    }

    vb *= (5.f / 96.f);             // LAMBDA_COORD / (B*3)
    vo *= (1.f / 96.f);             // / (B*3)
    vc *= (1.f / (4000.f * 96.f));  // / (n_obj*NUM_CLASSES) / (B*3)

    #pragma unroll
    for (int off = 1; off < 64; off <<= 1) {
        vb += __shfl_xor(vb, off, 64);
        vo += __shfl_xor(vo, off, 64);
        vc += __shfl_xor(vc, off, 64);
    }

    if (lane == 0) { red[wid][0] = vb; red[wid][1] = vo; red[wid][2] = vc; }
    __syncthreads();
    if (threadIdx.x == 0) {
        float b0 = red[0][0] + red[1][0] + red[2][0] + red[3][0];
        float o0 = red[0][1] + red[1][1] + red[2][1] + red[3][1];
        float c0s = red[0][2] + red[1][2] + red[2][2] + red[3][2];
        ((float4*)ws)[blockIdx.x] = make_float4(b0, o0, c0s, 0.f);
    }
}

__global__ __launch_bounds__(256)
void yolo_loss_final(const float* __restrict__ ws, float* __restrict__ out)
{
    const int lane = threadIdx.x & 63;
    const int wid  = threadIdx.x >> 6;
    __shared__ float red[4][3];

    float sb = 0.f, so = 0.f, sc = 0.f;
    for (int i = threadIdx.x; i < TOTAL_BLOCKS; i += 256) {
        const float4 v = ((const float4*)ws)[i];
        sb += v.x; so += v.y; sc += v.z;
    }
    #pragma unroll
    for (int off = 1; off < 64; off <<= 1) {
        sb += __shfl_xor(sb, off, 64);
        so += __shfl_xor(so, off, 64);
        sc += __shfl_xor(sc, off, 64);
    }
    if (lane == 0) { red[wid][0] = sb; red[wid][1] = so; red[wid][2] = sc; }
    __syncthreads();
    if (threadIdx.x == 0) {
        float b0 = red[0][0] + red[1][0] + red[2][0] + red[3][0];
        float o0 = red[0][1] + red[1][1] + red[2][1] + red[3][1];
        float c0 = red[0][2] + red[1][2] + red[2][2] + red[3][2];
        out[0] = b0;
        out[1] = o0;
        out[2] = c0;
        out[3] = b0 + o0 + c0;
    }
}

extern "C" void kernel_launch(void* const* d_in, const int* in_sizes, int n_in,
                              void* d_out, int out_size, void* d_ws, size_t ws_size,
                              hipStream_t stream) {
    const float* p3 = (const float*)d_in[0];
    const float* p4 = (const float*)d_in[1];
    const float* p5 = (const float*)d_in[2];
    const float* tb = (const float*)d_in[3];
    const int*   tc = (const int*)d_in[4];
    float* out = (float*)d_out;
    float* ws  = (float*)d_ws;   // needs TOTAL_BLOCKS*16 B = 12.7 KB

    hipLaunchKernelGGL(yolo_loss_partial,
                       dim3(TOTAL_BLOCKS), dim3(256), 0, stream,
                       p3, p4, p5, tb, tc, ws);
    hipLaunchKernelGGL(yolo_loss_final,
                       dim3(1), dim3(256), 0, stream,
                       ws, out);
}